// Round 5
// baseline (138.933 us; speedup 1.0000x reference)
//
#include <hip/hip_runtime.h>

#define NE    512
#define DIM   64
#define NROWS 131072            // 32*64*64
#define QELEMS (NROWS * DIM)    // 8388608

// ---- output layout (flat f32, reference return order) ----
#define OFF_Q     0
#define OFF_LOSS  8388608
#define OFF_INDS  8388609
#define OFF_NEMB  8519681       // OFF_INDS + 131072
#define OFF_NCS   8552449       // OFF_NEMB + 32768
#define OFF_NEA   8552961       // OFF_NCS  + 512

// ---- workspace layout (float-unit offsets) ----
#define WS_EMBT    0            // [512][64] f32 transposed codebook (e-major)
#define WS_ENORM   32768        // [512] f32 ||e||^2
#define WS_ESUM    33280        // [512][64] f32 segment sums (e-major, atomic)
#define WS_COUNTSF 66048        // [512] f32 counts (atomic)
#define WS_LOSS    66560        // [1] f32
#define WS_FRAG_F  66564        // [65536] ushort bf16 frags (hi then lo), 16B aligned
#define WS_END     99332

typedef __attribute__((ext_vector_type(8))) short short8;
typedef __attribute__((ext_vector_type(4))) float float4v;

__device__ inline unsigned short bf16_rne(float v) {
    unsigned u = __float_as_uint(v);
    u += 0x7fff + ((u >> 16) & 1);
    return (unsigned short)(u >> 16);
}

// insert candidate p into ascending best-3 (b0<=b1<=b2): 3 VALU ops
#define INS3(p, b0, b1, b2)                          \
    do {                                             \
        float _p = (p);                              \
        b2 = __builtin_amdgcn_fmed3f(_p, b1, b2);    \
        b1 = __builtin_amdgcn_fmed3f(_p, b0, b1);    \
        b0 = fminf(_p, b0);                          \
    } while (0)

// ---------------------------------------------------------------------------
// init: embT + enorm, zero esum/counts/loss, build pre-swizzled bf16 frags.
// grid = 389 x 256.
__global__ __launch_bounds__(256) void k_init(const float* __restrict__ embed,
                                              float* __restrict__ wsf) {
    int tid = blockIdx.x * 256 + threadIdx.x;
    if (tid < 32768) {
        int e = tid >> 6, d = tid & 63;
        wsf[WS_EMBT + tid] = embed[d * NE + e];          // embT[e][d]
    } else if (tid < 33280) {
        int e = tid - 32768;
        float s = 0.f;
        for (int d = 0; d < DIM; ++d) {
            float v = embed[d * NE + e];
            s = fmaf(v, v, s);
        }
        wsf[WS_ENORM + e] = s;
    } else if (tid < 66561) {
        wsf[tid] = 0.f;                                  // ESUM + COUNTSF + LOSS
    } else if (tid >= 66564 && tid < WS_END) {
        // frag build: ft in [0,32768): value embed[k][n] split to bf16 hi/lo.
        // layout: [t(32)][kt(2)][lane(64)][j(8)]; k = kt*32 + 8*(lane>>4) + j,
        //         n = 16*t + (lane&15)
        int ft = tid - 66564;
        int j  = ft & 7;
        int l  = (ft >> 3) & 63;
        int kt = (ft >> 9) & 1;
        int t  = ft >> 10;
        int k  = kt * 32 + 8 * (l >> 4) + j;
        int n  = 16 * t + (l & 15);
        float v = embed[k * NE + n];
        unsigned short hi = bf16_rne(v);
        float fhi = __uint_as_float((unsigned)hi << 16);
        unsigned short lo = bf16_rne(v - fhi);
        unsigned short* fh = (unsigned short*)(wsf + WS_FRAG_F);
        fh[ft]         = hi;
        fh[32768 + ft] = lo;
    }
}

// ---------------------------------------------------------------------------
// fused: split-bf16 MFMA argmin (packed best-3 via min/med3) + fp64 re-rank
// + quantize + loss + histogram + LDS segment-sum + atomic flush.
// block = 1024 (16 waves x 32 rows), grid = 256.
// LDS: 128KB frags (reused as esum after k-loop) + 2KB enorm + 2KB hist + 64B.
__global__ __launch_bounds__(1024, 4) void k_argmin(const float* __restrict__ in,
                                                    float* __restrict__ wsf,
                                                    float* __restrict__ inds_out,
                                                    float* __restrict__ qout) {
    extern __shared__ char smem[];
    short* lhi = (short*)smem;                 // 32768 shorts
    short* llo = lhi + 32768;                  // 32768 shorts
    float* len = (float*)(llo + 32768);        // 512 f32
    int*   lh  = (int*)(len + 512);            // 512 int
    float* lwr = (float*)(lh + 512);           // 16 f32

    // stage frags (128KB) + enorm; zero hist
    {
        const int4* src = (const int4*)(wsf + WS_FRAG_F);
        int4* dst = (int4*)lhi;
        for (int i = threadIdx.x; i < 8192; i += 1024) dst[i] = src[i];
        if (threadIdx.x < 512) {
            len[threadIdx.x] = wsf[WS_ENORM + threadIdx.x];
            lh[threadIdx.x] = 0;
        }
    }
    __syncthreads();

    const int w = threadIdx.x >> 6, l = threadIdx.x & 63;
    const int g = l >> 4, c = l & 15;
    const int rowbase = blockIdx.x * 512 + w * 32;

    // A fragments: rows (l&15), k-slots 8g..8g+7 per ktile, split hi/lo
    short8 ahi[2][2], alo[2][2];
#pragma unroll
    for (int mt = 0; mt < 2; ++mt) {
        const float* xr = in + (size_t)(rowbase + mt * 16 + c) * DIM;
#pragma unroll
        for (int kt = 0; kt < 2; ++kt) {
            float4v x0 = *(const float4v*)(xr + kt * 32 + 8 * g);
            float4v x1 = *(const float4v*)(xr + kt * 32 + 8 * g + 4);
            float a[8] = {x0[0], x0[1], x0[2], x0[3], x1[0], x1[1], x1[2], x1[3]};
            short8 h, lo8;
#pragma unroll
            for (int j = 0; j < 8; ++j) {
                unsigned short hb = bf16_rne(a[j]);
                float fhi = __uint_as_float((unsigned)hb << 16);
                h[j]   = (short)hb;
                lo8[j] = (short)bf16_rne(a[j] - fhi);
            }
            ahi[mt][kt] = h;
            alo[mt][kt] = lo8;
        }
    }

    // packed best-3 per slot: fp32 dist with low 9 mantissa bits = code index
    float b3[2][4][3];
#pragma unroll
    for (int mt = 0; mt < 2; ++mt)
#pragma unroll
        for (int j = 0; j < 4; ++j) {
            b3[mt][j][0] = 3.4e38f; b3[mt][j][1] = 3.4e38f; b3[mt][j][2] = 3.4e38f;
        }

    for (int t = 0; t < 32; ++t) {
        short8 bh0 = *(const short8*)(lhi + (t * 2 + 0) * 512 + l * 8);
        short8 bh1 = *(const short8*)(lhi + (t * 2 + 1) * 512 + l * 8);
        short8 bl0 = *(const short8*)(llo + (t * 2 + 0) * 512 + l * 8);
        short8 bl1 = *(const short8*)(llo + (t * 2 + 1) * 512 + l * 8);
        float4v acc0 = {0.f, 0.f, 0.f, 0.f};
        float4v acc1 = {0.f, 0.f, 0.f, 0.f};
        acc0 = __builtin_amdgcn_mfma_f32_16x16x32_bf16(ahi[0][0], bh0, acc0, 0, 0, 0);
        acc0 = __builtin_amdgcn_mfma_f32_16x16x32_bf16(ahi[0][1], bh1, acc0, 0, 0, 0);
        acc0 = __builtin_amdgcn_mfma_f32_16x16x32_bf16(alo[0][0], bh0, acc0, 0, 0, 0);
        acc0 = __builtin_amdgcn_mfma_f32_16x16x32_bf16(alo[0][1], bh1, acc0, 0, 0, 0);
        acc0 = __builtin_amdgcn_mfma_f32_16x16x32_bf16(ahi[0][0], bl0, acc0, 0, 0, 0);
        acc0 = __builtin_amdgcn_mfma_f32_16x16x32_bf16(ahi[0][1], bl1, acc0, 0, 0, 0);
        acc1 = __builtin_amdgcn_mfma_f32_16x16x32_bf16(ahi[1][0], bh0, acc1, 0, 0, 0);
        acc1 = __builtin_amdgcn_mfma_f32_16x16x32_bf16(ahi[1][1], bh1, acc1, 0, 0, 0);
        acc1 = __builtin_amdgcn_mfma_f32_16x16x32_bf16(alo[1][0], bh0, acc1, 0, 0, 0);
        acc1 = __builtin_amdgcn_mfma_f32_16x16x32_bf16(alo[1][1], bh1, acc1, 0, 0, 0);
        acc1 = __builtin_amdgcn_mfma_f32_16x16x32_bf16(ahi[1][0], bl0, acc1, 0, 0, 0);
        acc1 = __builtin_amdgcn_mfma_f32_16x16x32_bf16(ahi[1][1], bl1, acc1, 0, 0, 0);

        int n = t * 16 + c;
        float en = len[n];
#pragma unroll
        for (int j = 0; j < 4; ++j) {
            float d0 = fmaf(-2.f, acc0[j], en);
            float p0 = __uint_as_float((__float_as_uint(d0) & 0xFFFFFE00u) | (unsigned)n);
            INS3(p0, b3[0][j][0], b3[0][j][1], b3[0][j][2]);
            float d1 = fmaf(-2.f, acc1[j], en);
            float p1 = __uint_as_float((__float_as_uint(d1) & 0xFFFFFE00u) | (unsigned)n);
            INS3(p1, b3[1][j][0], b3[1][j][1], b3[1][j][2]);
        }
    }

    // per-slot: cross-lane best-3 merge, fp64 re-rank of 3, quantize + loss
    float lsum = 0.f;
    int idxsel[2][4];
#pragma unroll
    for (int mt = 0; mt < 2; ++mt)
#pragma unroll
        for (int j = 0; j < 4; ++j) {
            float c0 = b3[mt][j][0], c1 = b3[mt][j][1], c2 = b3[mt][j][2];
#pragma unroll
            for (int m = 1; m < 16; m <<= 1) {
                float o0 = __shfl_xor(c0, m, 64);
                float o1 = __shfl_xor(c1, m, 64);
                float o2 = __shfl_xor(c2, m, 64);
                INS3(o0, c0, c1, c2);
                INS3(o1, c0, c1, c2);
                INS3(o2, c0, c1, c2);
            }
            int i0 = (int)(__float_as_uint(c0) & 0x1FFu);
            int i1 = (int)(__float_as_uint(c1) & 0x1FFu);
            int i2 = (int)(__float_as_uint(c2) & 0x1FFu);

            int row = rowbase + mt * 16 + 4 * g + j;     // C/D row = (l>>4)*4 + reg
            float4v x4  = *(const float4v*)(in + (size_t)row * DIM + 4 * c);
            float4v e0v = *(const float4v*)(wsf + WS_EMBT + i0 * DIM + 4 * c);
            float4v e1v = *(const float4v*)(wsf + WS_EMBT + i1 * DIM + 4 * c);
            float4v e2v = *(const float4v*)(wsf + WS_EMBT + i2 * DIM + 4 * c);
            double s0 = 0.0, s1 = 0.0, s2 = 0.0;
#pragma unroll
            for (int q = 0; q < 4; ++q) {
                double xd = (double)x4[q];
                double a = (double)e0v[q]; s0 += a * (a - 2.0 * xd);
                double b = (double)e1v[q]; s1 += b * (b - 2.0 * xd);
                double d = (double)e2v[q]; s2 += d * (d - 2.0 * xd);
            }
#pragma unroll
            for (int m = 1; m < 16; m <<= 1) {
                s0 += __shfl_xor(s0, m, 64);
                s1 += __shfl_xor(s1, m, 64);
                s2 += __shfl_xor(s2, m, 64);
            }
            double sb = s0; int ib = i0; float4v qv = e0v;
            if (s1 < sb || (s1 == sb && i1 < ib)) { sb = s1; ib = i1; qv = e1v; }
            if (s2 < sb || (s2 == sb && i2 < ib)) { sb = s2; ib = i2; qv = e2v; }
            idxsel[mt][j] = ib;

            *(float4v*)(qout + (size_t)row * DIM + 4 * c) = qv;
            float4v df = qv - x4;
            lsum += df[0] * df[0] + df[1] * df[1] + df[2] * df[2] + df[3] * df[3];
            if (c == 0) {
                inds_out[row] = (float)ib;
                atomicAdd(&lh[ib], 1);
            }
        }

    // loss partial -> LDS (lwr lives outside the frag region)
    for (int off = 32; off; off >>= 1) lsum += __shfl_down(lsum, off, 64);
    if (l == 0) lwr[w] = lsum;

    // ---- backend: segment-sum in LDS (reuse dead 128KB frag region) ----
    __syncthreads();                           // frag reads + lwr writes done
    float* lesum = (float*)smem;               // [512][64] f32
    for (int i = threadIdx.x; i < 32768; i += 1024) lesum[i] = 0.f;
    __syncthreads();
#pragma unroll
    for (int o = 0; o < 32; ++o) {
        int mt = o >> 4, gg = (o & 15) >> 2, jj = o & 3;
        int code = __shfl(idxsel[mt][jj], gg * 16, 64);   // wave-uniform
        float x = in[(size_t)(rowbase + o) * DIM + l];
        atomicAdd(&lesum[code * DIM + l], x);             // 64 consec addrs
    }
    __syncthreads();
    // flush: esum (coalesced wave atomics), counts, loss
    for (int k = 0; k < 32; ++k) {
        int i = k * 1024 + threadIdx.x;
        float v = lesum[i];
        if (v != 0.f) atomicAdd(&wsf[WS_ESUM + i], v);
    }
    if (threadIdx.x < 512) {
        int cnt = lh[threadIdx.x];
        if (cnt) atomicAdd(&wsf[WS_COUNTSF + threadIdx.x], (float)cnt);
    }
    if (threadIdx.x == 0) {
        float s = 0.f;
        for (int i = 0; i < 16; ++i) s += lwr[i];
        atomicAdd(&wsf[WS_LOSS], s);
    }
}

// ---------------------------------------------------------------------------
// finalize: EMA buffers + normalized codebook + loss scale. One block.
__global__ __launch_bounds__(512) void k_final(const float* __restrict__ wsf,
                                               const float* __restrict__ cs_in,
                                               const float* __restrict__ eavg_in,
                                               float* __restrict__ out) {
    __shared__ float sred[512];
    int t = threadIdx.x;
    float c = 0.99f * cs_in[t] + 0.01f * wsf[WS_COUNTSF + t];
    out[OFF_NCS + t] = c;
    sred[t] = c;
    __syncthreads();
    for (int s = 256; s; s >>= 1) {
        if (t < s) sred[t] += sred[t + s];
        __syncthreads();
    }
    float n = sred[0];
    float csv = (c + 1e-5f) / (n + NE * 1e-5f) * n;
    for (int i = t; i < 32768; i += 512) {               // i & 511 == t, d = i>>9
        float nea = 0.99f * eavg_in[i] + 0.01f * wsf[WS_ESUM + t * DIM + (i >> 9)];
        out[OFF_NEA + i]  = nea;
        out[OFF_NEMB + i] = nea / csv;
    }
    if (t == 0) out[OFF_LOSS] = wsf[WS_LOSS] * (1.25f / 8388608.0f);
}

// ---------------------------------------------------------------------------
extern "C" void kernel_launch(void* const* d_in, const int* in_sizes, int n_in,
                              void* d_out, int out_size, void* d_ws, size_t ws_size,
                              hipStream_t stream) {
    const float* in    = (const float*)d_in[0];
    const float* embed = (const float*)d_in[1];
    const float* cs    = (const float*)d_in[2];
    const float* eavg  = (const float*)d_in[3];
    float* out = (float*)d_out;
    float* wsf = (float*)d_ws;

    k_init   <<<389, 256, 0, stream>>>(embed, wsf);
    k_argmin <<<256, 1024, 135232, stream>>>(in, wsf, out + OFF_INDS, out + OFF_Q);
    k_final  <<<1, 512, 0, stream>>>(wsf, cs, eavg, out);
}

// Round 6
// 113.306 us; speedup vs baseline: 1.2262x; 1.2262x over previous
//
#include <hip/hip_runtime.h>

#define NE    512
#define DIM   64
#define NROWS 131072            // 32*64*64
#define QELEMS (NROWS * DIM)    // 8388608

// ---- output layout (flat f32, reference return order) ----
#define OFF_Q     0
#define OFF_LOSS  8388608
#define OFF_INDS  8388609
#define OFF_NEMB  8519681       // OFF_INDS + 131072
#define OFF_NCS   8552449       // OFF_NEMB + 32768
#define OFF_NEA   8552961       // OFF_NCS  + 512

// ---- workspace layout (float-unit offsets) ----
#define WS_EMBT    0            // [512][64] f32 transposed codebook (e-major)
#define WS_ENORM   32768        // [512] f32 ||e||^2
#define WS_ESUM    33280        // [512][64] f32 segment sums (fallback mode)
#define WS_COUNTSF 66048        // [512] f32 counts (atomic)
#define WS_LOSS    66560        // [1] f32
#define WS_FRAG_F  66564        // [65536] ushort bf16 frags (hi then lo), 16B aligned
#define WS_END     99332
#define WS_PART    99584        // [256][32768] f32 private esum partials (mode 1)

typedef __attribute__((ext_vector_type(8))) short short8;
typedef __attribute__((ext_vector_type(4))) float float4v;

__device__ inline unsigned short bf16_rne(float v) {
    unsigned u = __float_as_uint(v);
    u += 0x7fff + ((u >> 16) & 1);
    return (unsigned short)(u >> 16);
}

// insert candidate p into ascending best-3 (b0<=b1<=b2): 3 VALU ops
#define INS3(p, b0, b1, b2)                          \
    do {                                             \
        float _p = (p);                              \
        b2 = __builtin_amdgcn_fmed3f(_p, b1, b2);    \
        b1 = __builtin_amdgcn_fmed3f(_p, b0, b1);    \
        b0 = fminf(_p, b0);                          \
    } while (0)

// ---------------------------------------------------------------------------
// init: embT + enorm, zero esum/counts/loss, build pre-swizzled bf16 frags.
// grid = 389 x 256.
__global__ __launch_bounds__(256) void k_init(const float* __restrict__ embed,
                                              float* __restrict__ wsf) {
    int tid = blockIdx.x * 256 + threadIdx.x;
    if (tid < 32768) {
        int e = tid >> 6, d = tid & 63;
        wsf[WS_EMBT + tid] = embed[d * NE + e];          // embT[e][d]
    } else if (tid < 33280) {
        int e = tid - 32768;
        float s = 0.f;
        for (int d = 0; d < DIM; ++d) {
            float v = embed[d * NE + e];
            s = fmaf(v, v, s);
        }
        wsf[WS_ENORM + e] = s;
    } else if (tid < 66561) {
        wsf[tid] = 0.f;                                  // ESUM + COUNTSF + LOSS
    } else if (tid >= 66564 && tid < WS_END) {
        // frag build: ft in [0,32768): value embed[k][n] split to bf16 hi/lo.
        // layout: [t(32)][kt(2)][lane(64)][j(8)]; k = kt*32 + 8*(lane>>4) + j,
        //         n = 16*t + (lane&15)
        int ft = tid - 66564;
        int j  = ft & 7;
        int l  = (ft >> 3) & 63;
        int kt = (ft >> 9) & 1;
        int t  = ft >> 10;
        int k  = kt * 32 + 8 * (l >> 4) + j;
        int n  = 16 * t + (l & 15);
        float v = embed[k * NE + n];
        unsigned short hi = bf16_rne(v);
        float fhi = __uint_as_float((unsigned)hi << 16);
        unsigned short lo = bf16_rne(v - fhi);
        unsigned short* fh = (unsigned short*)(wsf + WS_FRAG_F);
        fh[ft]         = hi;
        fh[32768 + ft] = lo;
    }
}

// ---------------------------------------------------------------------------
// fused: split-bf16 MFMA argmin (packed best-3) + fp64 re-rank + quantize +
// loss + histogram + LDS segment-sum (atomics folded into rerank) + RMW-free
// private-partial flush (mode 1) or atomic flush (mode 0).
// block = 1024 (16 waves x 32 rows), grid = 256.
__global__ __launch_bounds__(1024, 4) void k_argmin(const float* __restrict__ in,
                                                    float* __restrict__ wsf,
                                                    float* __restrict__ part,
                                                    int mode,
                                                    float* __restrict__ inds_out,
                                                    float* __restrict__ qout) {
    extern __shared__ char smem[];
    short* lhi = (short*)smem;                 // 32768 shorts
    short* llo = lhi + 32768;                  // 32768 shorts
    float* len = (float*)(llo + 32768);        // 512 f32
    int*   lh  = (int*)(len + 512);            // 512 int
    float* lwr = (float*)(lh + 512);           // 16 f32

    // stage frags (128KB) + enorm; zero hist
    {
        const int4* src = (const int4*)(wsf + WS_FRAG_F);
        int4* dst = (int4*)lhi;
        for (int i = threadIdx.x; i < 8192; i += 1024) dst[i] = src[i];
        if (threadIdx.x < 512) {
            len[threadIdx.x] = wsf[WS_ENORM + threadIdx.x];
            lh[threadIdx.x] = 0;
        }
    }
    __syncthreads();

    const int w = threadIdx.x >> 6, l = threadIdx.x & 63;
    const int g = l >> 4, c = l & 15;
    const int rowbase = blockIdx.x * 512 + w * 32;

    // A fragments: rows (l&15), k-slots 8g..8g+7 per ktile, split hi/lo
    short8 ahi[2][2], alo[2][2];
#pragma unroll
    for (int mt = 0; mt < 2; ++mt) {
        const float* xr = in + (size_t)(rowbase + mt * 16 + c) * DIM;
#pragma unroll
        for (int kt = 0; kt < 2; ++kt) {
            float4v x0 = *(const float4v*)(xr + kt * 32 + 8 * g);
            float4v x1 = *(const float4v*)(xr + kt * 32 + 8 * g + 4);
            float a[8] = {x0[0], x0[1], x0[2], x0[3], x1[0], x1[1], x1[2], x1[3]};
            short8 h, lo8;
#pragma unroll
            for (int j = 0; j < 8; ++j) {
                unsigned short hb = bf16_rne(a[j]);
                float fhi = __uint_as_float((unsigned)hb << 16);
                h[j]   = (short)hb;
                lo8[j] = (short)bf16_rne(a[j] - fhi);
            }
            ahi[mt][kt] = h;
            alo[mt][kt] = lo8;
        }
    }

    // packed best-3 per slot: fp32 dist with low 9 mantissa bits = code index
    float b3[2][4][3];
#pragma unroll
    for (int mt = 0; mt < 2; ++mt)
#pragma unroll
        for (int j = 0; j < 4; ++j) {
            b3[mt][j][0] = 3.4e38f; b3[mt][j][1] = 3.4e38f; b3[mt][j][2] = 3.4e38f;
        }

    for (int t = 0; t < 32; ++t) {
        short8 bh0 = *(const short8*)(lhi + (t * 2 + 0) * 512 + l * 8);
        short8 bh1 = *(const short8*)(lhi + (t * 2 + 1) * 512 + l * 8);
        short8 bl0 = *(const short8*)(llo + (t * 2 + 0) * 512 + l * 8);
        short8 bl1 = *(const short8*)(llo + (t * 2 + 1) * 512 + l * 8);
        float4v acc0 = {0.f, 0.f, 0.f, 0.f};
        float4v acc1 = {0.f, 0.f, 0.f, 0.f};
        acc0 = __builtin_amdgcn_mfma_f32_16x16x32_bf16(ahi[0][0], bh0, acc0, 0, 0, 0);
        acc0 = __builtin_amdgcn_mfma_f32_16x16x32_bf16(ahi[0][1], bh1, acc0, 0, 0, 0);
        acc0 = __builtin_amdgcn_mfma_f32_16x16x32_bf16(alo[0][0], bh0, acc0, 0, 0, 0);
        acc0 = __builtin_amdgcn_mfma_f32_16x16x32_bf16(alo[0][1], bh1, acc0, 0, 0, 0);
        acc0 = __builtin_amdgcn_mfma_f32_16x16x32_bf16(ahi[0][0], bl0, acc0, 0, 0, 0);
        acc0 = __builtin_amdgcn_mfma_f32_16x16x32_bf16(ahi[0][1], bl1, acc0, 0, 0, 0);
        acc1 = __builtin_amdgcn_mfma_f32_16x16x32_bf16(ahi[1][0], bh0, acc1, 0, 0, 0);
        acc1 = __builtin_amdgcn_mfma_f32_16x16x32_bf16(ahi[1][1], bh1, acc1, 0, 0, 0);
        acc1 = __builtin_amdgcn_mfma_f32_16x16x32_bf16(alo[1][0], bh0, acc1, 0, 0, 0);
        acc1 = __builtin_amdgcn_mfma_f32_16x16x32_bf16(alo[1][1], bh1, acc1, 0, 0, 0);
        acc1 = __builtin_amdgcn_mfma_f32_16x16x32_bf16(ahi[1][0], bl0, acc1, 0, 0, 0);
        acc1 = __builtin_amdgcn_mfma_f32_16x16x32_bf16(ahi[1][1], bl1, acc1, 0, 0, 0);

        int n = t * 16 + c;
        float en = len[n];
#pragma unroll
        for (int j = 0; j < 4; ++j) {
            float d0 = fmaf(-2.f, acc0[j], en);
            float p0 = __uint_as_float((__float_as_uint(d0) & 0xFFFFFE00u) | (unsigned)n);
            INS3(p0, b3[0][j][0], b3[0][j][1], b3[0][j][2]);
            float d1 = fmaf(-2.f, acc1[j], en);
            float p1 = __uint_as_float((__float_as_uint(d1) & 0xFFFFFE00u) | (unsigned)n);
            INS3(p1, b3[1][j][0], b3[1][j][1], b3[1][j][2]);
        }
    }

    // frag LDS is dead now -> reuse as per-block esum accumulator
    __syncthreads();
    float* lesum = (float*)smem;               // [512][64] f32
    for (int i = threadIdx.x; i < 32768; i += 1024) lesum[i] = 0.f;
    __syncthreads();

    // per-slot: cross-lane best-3 merge, fp64 re-rank of 3, quantize + loss
    // + LDS segment-sum scatter (each lane adds its 4 dims of the row)
    float lsum = 0.f;
#pragma unroll
    for (int mt = 0; mt < 2; ++mt)
#pragma unroll
        for (int j = 0; j < 4; ++j) {
            float c0 = b3[mt][j][0], c1 = b3[mt][j][1], c2 = b3[mt][j][2];
#pragma unroll
            for (int m = 1; m < 16; m <<= 1) {
                float o0 = __shfl_xor(c0, m, 64);
                float o1 = __shfl_xor(c1, m, 64);
                float o2 = __shfl_xor(c2, m, 64);
                INS3(o0, c0, c1, c2);
                INS3(o1, c0, c1, c2);
                INS3(o2, c0, c1, c2);
            }
            int i0 = (int)(__float_as_uint(c0) & 0x1FFu);
            int i1 = (int)(__float_as_uint(c1) & 0x1FFu);
            int i2 = (int)(__float_as_uint(c2) & 0x1FFu);

            int row = rowbase + mt * 16 + 4 * g + j;     // C/D row = (l>>4)*4 + reg
            float4v x4  = *(const float4v*)(in + (size_t)row * DIM + 4 * c);
            float4v e0v = *(const float4v*)(wsf + WS_EMBT + i0 * DIM + 4 * c);
            float4v e1v = *(const float4v*)(wsf + WS_EMBT + i1 * DIM + 4 * c);
            float4v e2v = *(const float4v*)(wsf + WS_EMBT + i2 * DIM + 4 * c);
            double s0 = 0.0, s1 = 0.0, s2 = 0.0;
#pragma unroll
            for (int q = 0; q < 4; ++q) {
                double xd = (double)x4[q];
                double a = (double)e0v[q]; s0 += a * (a - 2.0 * xd);
                double b = (double)e1v[q]; s1 += b * (b - 2.0 * xd);
                double d = (double)e2v[q]; s2 += d * (d - 2.0 * xd);
            }
#pragma unroll
            for (int m = 1; m < 16; m <<= 1) {
                s0 += __shfl_xor(s0, m, 64);
                s1 += __shfl_xor(s1, m, 64);
                s2 += __shfl_xor(s2, m, 64);
            }
            double sb = s0; int ib = i0; float4v qv = e0v;
            if (s1 < sb || (s1 == sb && i1 < ib)) { sb = s1; ib = i1; qv = e1v; }
            if (s2 < sb || (s2 == sb && i2 < ib)) { sb = s2; ib = i2; qv = e2v; }

            *(float4v*)(qout + (size_t)row * DIM + 4 * c) = qv;
            float4v df = qv - x4;
            lsum += df[0] * df[0] + df[1] * df[1] + df[2] * df[2] + df[3] * df[3];
#pragma unroll
            for (int q = 0; q < 4; ++q)
                atomicAdd(&lesum[ib * DIM + 4 * c + q], x4[q]);
            if (c == 0) {
                inds_out[row] = (float)ib;
                atomicAdd(&lh[ib], 1);
            }
        }

    // loss partial -> LDS (lwr lives outside the frag/lesum region)
    for (int off = 32; off; off >>= 1) lsum += __shfl_down(lsum, off, 64);
    if (l == 0) lwr[w] = lsum;
    __syncthreads();

    // ---- flush ----
    if (mode) {
        float* dst = part + (size_t)blockIdx.x * 32768;  // private: plain stores
        for (int k = 0; k < 32; ++k) {
            int i = k * 1024 + threadIdx.x;
            dst[i] = lesum[i];
        }
    } else {
        for (int k = 0; k < 32; ++k) {                   // fallback: atomic RMW
            int i = k * 1024 + threadIdx.x;
            float v = lesum[i];
            if (v != 0.f) atomicAdd(&wsf[WS_ESUM + i], v);
        }
    }
    if (threadIdx.x < 512) {
        int cnt = lh[threadIdx.x];
        if (cnt) atomicAdd(&wsf[WS_COUNTSF + threadIdx.x], (float)cnt);
    }
    if (threadIdx.x == 0) {
        float s = 0.f;
        for (int i = 0; i < 16; ++i) s += lwr[i];
        atomicAdd(&wsf[WS_LOSS], s);
    }
}

// ---------------------------------------------------------------------------
// finalize: reduce 256 esum partials (mode 1) or read esum (mode 0), EMA
// buffers + normalized codebook + loss. grid = 256 x 256; block b owns
// esum slots [b*128, b*128+128) = codes 2b, 2b+1.
__global__ __launch_bounds__(256) void k_final(const float* __restrict__ wsf,
                                               const float* __restrict__ part,
                                               int mode,
                                               const float* __restrict__ cs_in,
                                               const float* __restrict__ eavg_in,
                                               float* __restrict__ out) {
    __shared__ float red[256];
    __shared__ float tot[128];
    int b = blockIdx.x, t = threadIdx.x;

    // n = sum over codes of (0.99*cs + 0.01*count)  (counts final before launch)
    float nacc = 0.f;
    for (int e = t; e < NE; e += 256)
        nacc += 0.99f * cs_in[e] + 0.01f * wsf[WS_COUNTSF + e];
    red[t] = nacc;
    __syncthreads();
    for (int s = 128; s; s >>= 1) {
        if (t < s) red[t] += red[t + s];
        __syncthreads();
    }
    float n = red[0];
    __syncthreads();

    // reduce partials for my 128 slots (two threads per slot, fixed order)
    int base = b * 128;
    int s = t & 127, half = t >> 7;
    float sum = 0.f;
    if (mode) {
        for (int p = 0; p < 128; ++p)
            sum += part[(size_t)(half * 128 + p) * 32768 + base + s];
    } else {
        sum = half ? 0.f : wsf[WS_ESUM + base + s];
    }
    red[t] = sum;
    __syncthreads();
    if (t < 128) tot[t] = red[t] + red[t + 128];
    __syncthreads();

    if (t < 128) {
        int e = b * 2 + (t >> 6);
        int d = t & 63;
        float c = 0.99f * cs_in[e] + 0.01f * wsf[WS_COUNTSF + e];
        float csv = (c + 1e-5f) / (n + NE * 1e-5f) * n;
        float nea = 0.99f * eavg_in[d * NE + e] + 0.01f * tot[t];
        out[OFF_NEA + d * NE + e]  = nea;
        out[OFF_NEMB + d * NE + e] = nea / csv;
    }
    if (b == 0) {
        float c0 = 0.99f * cs_in[t] + 0.01f * wsf[WS_COUNTSF + t];
        float c1 = 0.99f * cs_in[t + 256] + 0.01f * wsf[WS_COUNTSF + t + 256];
        out[OFF_NCS + t]       = c0;
        out[OFF_NCS + t + 256] = c1;
        if (t == 0) out[OFF_LOSS] = wsf[WS_LOSS] * (1.25f / 8388608.0f);
    }
}

// ---------------------------------------------------------------------------
extern "C" void kernel_launch(void* const* d_in, const int* in_sizes, int n_in,
                              void* d_out, int out_size, void* d_ws, size_t ws_size,
                              hipStream_t stream) {
    const float* in    = (const float*)d_in[0];
    const float* embed = (const float*)d_in[1];
    const float* cs    = (const float*)d_in[2];
    const float* eavg  = (const float*)d_in[3];
    float* out = (float*)d_out;
    float* wsf = (float*)d_ws;

    size_t need = ((size_t)WS_PART + (size_t)256 * 32768) * sizeof(float);
    int mode = (ws_size >= need) ? 1 : 0;
    float* part = wsf + WS_PART;

    k_init   <<<389, 256, 0, stream>>>(embed, wsf);
    k_argmin <<<256, 1024, 135232, stream>>>(in, wsf, part, mode,
                                             out + OFF_INDS, out + OFF_Q);
    k_final  <<<256, 256, 0, stream>>>(wsf, part, mode, cs, eavg, out);
}